// Round 1
// baseline (143.131 us; speedup 1.0000x reference)
//
#include <hip/hip_runtime.h>

// ContextGenerator: B=32, D=NOTE_RES=64, T=4096, fp32 in/out.
// res[b,t] = sum_{L=low..min(63,up-1)} dm[b,L-1,t] * sum_{w<L} d_L[b,t,w]*pm[b,w,t]
// where d_L mixes pyramid levels: for L in [M,2M), pad=L-M:
//   d_L = [ x_l[0:2pad], x_{l+1}[pad:M] ],  x_l = down^l(rep[b,:,t]).
// Per-thread (one (b,t) per thread), all register-resident, fully unrolled.

#define TT 4096   // T; hard-coded (t = gid & 4095, b = gid >> 12)

// Accumulate one pyramid group's contribution (window lengths L = M .. 2M-1).
// p-prefix of q[] supplies the fine-level term; xa[] is the coarse level x_{l+1}.
template <int M>
__device__ __forceinline__ void group_accum(const float* __restrict__ dmb,
                                            const float* pmv, const float* xa,
                                            const float* q, int low, int up,
                                            float& res) {
#pragma unroll
  for (int pad = 0, _dummy = 0; pad < M; ++pad) {
    (void)_dummy;
  }
  float p = 0.f;
#pragma unroll
  for (int pad = 0; pad < M; ++pad) {
    const int L = M + pad;
    float s = p;  // = sum_{w<2*pad} x_l[w]*pm[w]
#pragma unroll
    for (int k = pad; k < M; ++k) s = fmaf(xa[k], pmv[k + pad], s);
    if (L >= low && L < up)  // uniform branch (scalar low/up)
      res = fmaf(dmb[(size_t)(M - 1 + pad) * TT], s, res);
    p += q[pad];
  }
}

// In-place downsample: from current level (length 2M) in xa[0:2M] produce the
// next level (length M) in xa[0:M], and the fine-level products q[0:M].
template <int M>
__device__ __forceinline__ void downsample(const float* pmv, float* xa,
                                           float* q) {
#pragma unroll
  for (int j = 0; j < M; ++j) {
    const float a = xa[2 * j];
    const float c = xa[2 * j + 1];
    q[j] = a * pmv[2 * j] + c * pmv[2 * j + 1];
    xa[j] = 0.5f * (a + c);
  }
}

__global__ __launch_bounds__(256, 2) void ContextGenerator_34875134444049_kernel(
    const float* __restrict__ rep, const float* __restrict__ dm,
    const float* __restrict__ pm, const int* __restrict__ lowp,
    const int* __restrict__ upp, float* __restrict__ out, int n) {
  const int gid = blockIdx.x * 256 + threadIdx.x;
  if (gid >= n) return;
  const int t = gid & (TT - 1);
  const int b = gid >> 12;
  const size_t base = (size_t)b * 64 * TT + (size_t)t;

  const int low = lowp[0];
  const int up = upp[0];

  const float* __restrict__ repb = rep + base;
  const float* __restrict__ dmb = dm + base;
  const float* __restrict__ pmb = pm + base;

  // position_mask rows 0..62 — resident for the whole kernel.
  float pmv[63];
#pragma unroll
  for (int w = 0; w < 63; ++w) pmv[w] = pmb[(size_t)w * TT];

  // Build level-1 (xa, 32 wide) and fine products q from streamed level-0 rep.
  float xa[32];
  float q[32];
#pragma unroll
  for (int j = 0; j < 32; ++j) {
    const float a = repb[(size_t)(2 * j) * TT];
    const float c = repb[(size_t)(2 * j + 1) * TT];
    xa[j] = 0.5f * (a + c);
    q[j] = a * pmv[2 * j] + c * pmv[2 * j + 1];
  }

  float res = 0.f;
  group_accum<32>(dmb, pmv, xa, q, low, up, res);  // L = 32..63
  downsample<16>(pmv, xa, q);
  group_accum<16>(dmb, pmv, xa, q, low, up, res);  // L = 16..31
  downsample<8>(pmv, xa, q);
  group_accum<8>(dmb, pmv, xa, q, low, up, res);   // L = 8..15
  downsample<4>(pmv, xa, q);
  group_accum<4>(dmb, pmv, xa, q, low, up, res);   // L = 4..7
  downsample<2>(pmv, xa, q);
  group_accum<2>(dmb, pmv, xa, q, low, up, res);   // L = 2..3
  downsample<1>(pmv, xa, q);
  group_accum<1>(dmb, pmv, xa, q, low, up, res);   // L = 1

  out[gid] = res;
}

extern "C" void kernel_launch(void* const* d_in, const int* in_sizes, int n_in,
                              void* d_out, int out_size, void* d_ws,
                              size_t ws_size, hipStream_t stream) {
  const float* rep = (const float*)d_in[0];
  const float* dm = (const float*)d_in[1];
  const float* pm = (const float*)d_in[2];
  const int* lowp = (const int*)d_in[3];
  const int* upp = (const int*)d_in[4];
  float* out = (float*)d_out;

  const int n = out_size;  // B*T = 131072
  const int blocks = (n + 255) / 256;
  ContextGenerator_34875134444049_kernel<<<blocks, 256, 0, stream>>>(
      rep, dm, pm, lowp, upp, out, n);
}

// Round 2
// 125.930 us; speedup vs baseline: 1.1366x; 1.1366x over previous
//
#include <hip/hip_runtime.h>

// ContextGenerator: B=32, D=NOTE_RES=64, T=4096, fp32.
// res[b,t] = sum_{L=low..min(63,up-1)} dm[b,L-1,t] * sum_{w<L} d_L[w]*pm[b,w,t]
// d_L for L in [M,2M), pad=L-M:  d_L = [ x_l[0:2pad], x_{l+1}[pad:M] ].
//
// R1 restructure: block = 4 waves sharing one 64-t slice.
//  - rep rows 0..63 + pm rows 0..62 staged to LDS via global_load_lds (async,
//    deep MLP) -> HBM-throughput-bound instead of per-thread latency-bound.
//  - L-sum split across waves (uniform role per wave, no divergence):
//    role0: group32 pads 0..5 (177 FMA), role1: pads 6..12 (161),
//    role2: pads 13..31 (190), role3: groups 16/8/4/2/1 (186).
//  - dm rows prefetched per-role into registers before the barrier.
//  - partials reduced through LDS.

#define TT 4096

__device__ __forceinline__ void async_load_f32(const float* g, float* l) {
  __builtin_amdgcn_global_load_lds(
      (const __attribute__((address_space(1))) void*)g,
      (__attribute__((address_space(3))) void*)l, 4, 0, 0);
}

// Waves 0-2: partial of group32 over pad range [P0, P1).
// dmr[i] = dm row (31 + P0 + i).
template <int P0, int P1>
__device__ __forceinline__ float role32(const float* __restrict__ lrep,
                                        const float* __restrict__ lpm,
                                        const float* dmr, int lane, int low,
                                        int up) {
  float xa[32 - P0];
#pragma unroll
  for (int k = P0; k < 32; ++k)
    xa[k - P0] = 0.5f * (lrep[(2 * k) * 64 + lane] + lrep[(2 * k + 1) * 64 + lane]);
  float q[P1 - 1];
#pragma unroll
  for (int j = 0; j < P1 - 1; ++j)
    q[j] = lrep[(2 * j) * 64 + lane] * lpm[(2 * j) * 64 + lane] +
           lrep[(2 * j + 1) * 64 + lane] * lpm[(2 * j + 1) * 64 + lane];
  float p = 0.f;
#pragma unroll
  for (int j = 0; j < P0; ++j) p += q[j];
  float res = 0.f;
#pragma unroll
  for (int pad = P0; pad < P1; ++pad) {
    const int L = 32 + pad;
    float s = p;  // sum_{w<2*pad} x0[w]*pm[w]
#pragma unroll
    for (int k = pad; k < 32; ++k)
      s = fmaf(xa[k - P0], lpm[(k + pad) * 64 + lane], s);
    if (L >= low && L < up) res = fmaf(dmr[pad - P0], s, res);
    if (pad + 1 < P1) p += q[pad];
  }
  return res;
}

// Wave 3 helpers: pyramid levels M=16..1. dmr[i] = dm row i (i in 0..30).
template <int M>
__device__ __forceinline__ void down_lds(const float* __restrict__ lpm, int lane,
                                         float* xa, float* q) {
#pragma unroll
  for (int j = 0; j < M; ++j) {
    const float a = xa[2 * j];
    const float c = xa[2 * j + 1];
    q[j] = a * lpm[(2 * j) * 64 + lane] + c * lpm[(2 * j + 1) * 64 + lane];
    xa[j] = 0.5f * (a + c);
  }
}

template <int M>
__device__ __forceinline__ void acc_lds(const float* __restrict__ lpm,
                                        const float* dmr, int lane,
                                        const float* xa, const float* q, int low,
                                        int up, float& res) {
  float p = 0.f;
#pragma unroll
  for (int pad = 0; pad < M; ++pad) {
    const int L = M + pad;
    float s = p;
#pragma unroll
    for (int k = pad; k < M; ++k) s = fmaf(xa[k], lpm[(k + pad) * 64 + lane], s);
    if (L >= low && L < up) res = fmaf(dmr[M - 1 + pad], s, res);
    p += q[pad];
  }
}

__device__ __forceinline__ float role_tail(const float* __restrict__ lrep,
                                           const float* __restrict__ lpm,
                                           const float* dmr, int lane, int low,
                                           int up) {
  float xa[32];
#pragma unroll
  for (int k = 0; k < 32; ++k)
    xa[k] = 0.5f * (lrep[(2 * k) * 64 + lane] + lrep[(2 * k + 1) * 64 + lane]);
  float q[16];
  float res = 0.f;
  down_lds<16>(lpm, lane, xa, q);
  acc_lds<16>(lpm, dmr, lane, xa, q, low, up, res);
  down_lds<8>(lpm, lane, xa, q);
  acc_lds<8>(lpm, dmr, lane, xa, q, low, up, res);
  down_lds<4>(lpm, lane, xa, q);
  acc_lds<4>(lpm, dmr, lane, xa, q, low, up, res);
  down_lds<2>(lpm, lane, xa, q);
  acc_lds<2>(lpm, dmr, lane, xa, q, low, up, res);
  down_lds<1>(lpm, lane, xa, q);
  acc_lds<1>(lpm, dmr, lane, xa, q, low, up, res);
  return res;
}

__global__ __launch_bounds__(256, 4) void ContextGenerator_34875134444049_kernel(
    const float* __restrict__ rep, const float* __restrict__ dm,
    const float* __restrict__ pm, const int* __restrict__ lowp,
    const int* __restrict__ upp, float* __restrict__ out) {
  __shared__ float lds[128 * 64 + 4 * 64];  // [rep rows 0..63 | pm rows 0..62 | partials]
  const int wid = threadIdx.x >> 6;
  const int lane = threadIdx.x & 63;
  const int b = blockIdx.x >> 6;          // T/64 = 64 chunks per batch
  const int t0 = (blockIdx.x & 63) << 6;  // 64-t slice

  const size_t base = (size_t)b * 64 * TT + (size_t)t0;

  // --- async stage: rep rows 0..63 -> lds[0:64*64], pm rows 0..62 -> lds[64*64:...]
  for (int r = wid; r < 127; r += 4) {  // wave-uniform r
    const float* src = (r < 64) ? rep + base + (size_t)r * TT
                                : pm + base + (size_t)(r - 64) * TT;
    async_load_f32(src + lane, &lds[r * 64]);
  }

  const int low = lowp[0];
  const int up = upp[0];

  // --- per-role dm prefetch (independent of LDS; overlaps the staging wait)
  const float* dmb = dm + base + lane;
  float dmr[31];
  if (wid == 0) {
#pragma unroll
    for (int i = 0; i < 6; ++i) dmr[i] = dmb[(size_t)(31 + i) * TT];
  } else if (wid == 1) {
#pragma unroll
    for (int i = 0; i < 7; ++i) dmr[i] = dmb[(size_t)(37 + i) * TT];
  } else if (wid == 2) {
#pragma unroll
    for (int i = 0; i < 19; ++i) dmr[i] = dmb[(size_t)(44 + i) * TT];
  } else {
#pragma unroll
    for (int i = 0; i < 31; ++i) dmr[i] = dmb[(size_t)i * TT];
  }

  __syncthreads();  // drains global_load_lds (vmcnt) + barrier

  const float* lrep = lds;
  const float* lpm = lds + 64 * 64;

  float res;
  if (wid == 0)
    res = role32<0, 6>(lrep, lpm, dmr, lane, low, up);
  else if (wid == 1)
    res = role32<6, 13>(lrep, lpm, dmr, lane, low, up);
  else if (wid == 2)
    res = role32<13, 32>(lrep, lpm, dmr, lane, low, up);
  else
    res = role_tail(lrep, lpm, dmr, lane, low, up);

  float* part = lds + 128 * 64;
  part[wid * 64 + lane] = res;
  __syncthreads();

  if (threadIdx.x < 64) {
    const float r = part[threadIdx.x] + part[64 + threadIdx.x] +
                    part[128 + threadIdx.x] + part[192 + threadIdx.x];
    out[(size_t)b * TT + t0 + threadIdx.x] = r;
  }
}

extern "C" void kernel_launch(void* const* d_in, const int* in_sizes, int n_in,
                              void* d_out, int out_size, void* d_ws,
                              size_t ws_size, hipStream_t stream) {
  const float* rep = (const float*)d_in[0];
  const float* dm = (const float*)d_in[1];
  const float* pm = (const float*)d_in[2];
  const int* lowp = (const int*)d_in[3];
  const int* upp = (const int*)d_in[4];
  float* out = (float*)d_out;

  const int blocks = out_size / 64;  // 32 * 4096 / 64 = 2048
  ContextGenerator_34875134444049_kernel<<<blocks, 256, 0, stream>>>(
      rep, dm, pm, lowp, upp, out);
}